// Round 5
// baseline (397.234 us; speedup 1.0000x reference)
//
#include <hip/hip_runtime.h>
#include <math.h>

// Problem constants (match reference.py)
#define HS_D       1024   // input_size
#define HS_MAXLEN  24     // max Huffman path depth
#define HS_PAIRS   12     // step-pairs per example (24/2)
#define HS_PF_OFF  (1u << 21)  // float offset in ws for prefetch dummy sums

// ---------------------------------------------------------------------------
// Kernel 1: stream W and x sequentially to warm the 256 MiB Infinity Cache.
// Streaming reads are NOT outstanding-miss limited (~6.3 TB/s), whereas the
// random row gather plateaus at ~2.4 TB/s on cold HBM (R0-R3 evidence).
// After this pass the 237 MB working set is L3-resident and the gather's
// miss latency (and thus MSHR turnover) improves ~2x.
// Dummy sums are written to a far region of ws to prevent DCE.
// ---------------------------------------------------------------------------
__global__ __launch_bounds__(256) void hsm_prefetch_kernel(
    const float4* __restrict__ W4, int nW4,
    const float4* __restrict__ x4, int nx4,
    float* __restrict__ ws)
{
    const int tid    = blockIdx.x * blockDim.x + threadIdx.x;
    const int stride = gridDim.x * blockDim.x;
    float s = 0.0f;
    for (int i = tid; i < nW4; i += stride) {
        const float4 v = W4[i];
        s += v.x + v.y + v.z + v.w;
    }
    for (int i = tid; i < nx4; i += stride) {
        const float4 v = x4[i];
        s += v.x + v.y + v.z + v.w;
    }
    ws[HS_PF_OFF + tid] = s;   // DCE guard (never read back)
}

// ---------------------------------------------------------------------------
// Kernel 2: one WAVE per (example, step-pair) — the R2 structure (best
// measured). Each wave loads 2 W-row fragments (issued FIRST: these are the
// misses) + its x fragment, two dots, interleaved butterfly reduce, masked
// softplus. Result is stored to a PRIVATE ws slot (ws[gw]) — no atomics, no
// zero-init needed (every dispatched wave writes its slot exactly once).
// ---------------------------------------------------------------------------
__global__ __launch_bounds__(256) void hsm_pair_kernel(
    const float* __restrict__ x,      // [N_EX, D]
    const float* __restrict__ W,      // [N_DEC, D]
    const int*   __restrict__ t,      // [N_EX]
    const int*   __restrict__ paths,  // [V, MAX_LEN]
    const float* __restrict__ codes,  // [V, MAX_LEN]
    const int*   __restrict__ lens,   // [V]
    float*       __restrict__ ws)     // [N_EX*HS_PAIRS] per-wave slots
{
    const int tid  = threadIdx.x;
    const int lane = tid & 63;
    const int gw   = blockIdx.x * 4 + (tid >> 6);  // global wave id
    const int n    = gw / HS_PAIRS;                // example
    const int p    = gw % HS_PAIRS;                // step-pair

    const int leaf = t[n];                 // wave-uniform -> scalar load
    const int L    = lens[leaf];           // wave-uniform
    const int l0   = 2 * p;
    const int l1   = l0 + 1;
    if (l0 >= L) {                         // wave-uniform early exit
        if (lane == 0) ws[gw] = 0.0f;      // slot must be written (poisoned)
        return;
    }

    const int   node0 = paths[leaf * HS_MAXLEN + l0];
    const float c0    = codes[leaf * HS_MAXLEN + l0];
    const bool  v1    = (l1 < L);
    // Clamp invalid second step to node0: duplicate address -> cache hit.
    const int   node1 = v1 ? paths[leaf * HS_MAXLEN + l1] : node0;
    const float c1    = v1 ? codes[leaf * HS_MAXLEN + l1] : 1.0f;

    const float4* w0 = (const float4*)(W + (size_t)node0 * HS_D);
    const float4* w1 = (const float4*)(W + (size_t)node1 * HS_D);
    const float4* x4 = (const float4*)(x + (size_t)n     * HS_D);

    // Issue all 12 loads before consuming; W first (likelier misses).
    float4 wf0[4], wf1[4], xf[4];
#pragma unroll
    for (int j = 0; j < 4; ++j) wf0[j] = w0[j * 64 + lane];
#pragma unroll
    for (int j = 0; j < 4; ++j) wf1[j] = w1[j * 64 + lane];
#pragma unroll
    for (int j = 0; j < 4; ++j) xf[j]  = x4[j * 64 + lane];

    float d0 = 0.0f, d1 = 0.0f;
#pragma unroll
    for (int j = 0; j < 4; ++j) {
        d0 += xf[j].x * wf0[j].x + xf[j].y * wf0[j].y
            + xf[j].z * wf0[j].z + xf[j].w * wf0[j].w;
        d1 += xf[j].x * wf1[j].x + xf[j].y * wf1[j].y
            + xf[j].z * wf1[j].z + xf[j].w * wf1[j].w;
    }

    // Two interleaved 64-lane butterfly reductions.
#pragma unroll
    for (int off = 32; off > 0; off >>= 1) {
        d0 += __shfl_down(d0, off);
        d1 += __shfl_down(d1, off);
    }

    if (lane == 0) {
        const float z0 = -c0 * d0;
        float v = fmaxf(z0, 0.0f) + log1pf(expf(-fabsf(z0)));
        if (v1) {
            const float z1 = -c1 * d1;
            v += fmaxf(z1, 0.0f) + log1pf(expf(-fabsf(z1)));
        }
        ws[gw] = v;
    }
}

// ---------------------------------------------------------------------------
// Kernel 3: sum the per-wave slots -> scalar output. One 1024-thread block.
// ---------------------------------------------------------------------------
__global__ __launch_bounds__(1024) void hsm_finish_kernel(
    const float* __restrict__ ws, int n_slots, float* __restrict__ out)
{
    const int tid = threadIdx.x;
    float s = 0.0f;
    for (int i = tid; i < n_slots; i += 1024)
        s += ws[i];
#pragma unroll
    for (int off = 32; off > 0; off >>= 1)
        s += __shfl_down(s, off);
    __shared__ float sred[16];
    if ((tid & 63) == 0) sred[tid >> 6] = s;
    __syncthreads();
    if (tid == 0) {
        float tot = 0.0f;
#pragma unroll
        for (int w = 0; w < 16; ++w) tot += sred[w];
        out[0] = tot;
    }
}

extern "C" void kernel_launch(void* const* d_in, const int* in_sizes, int n_in,
                              void* d_out, int out_size, void* d_ws, size_t ws_size,
                              hipStream_t stream) {
    const float* x     = (const float*)d_in[0];
    const float* W     = (const float*)d_in[1];
    const int*   t     = (const int*)  d_in[2];
    const int*   paths = (const int*)  d_in[3];
    const float* codes = (const float*)d_in[4];
    const int*   lens  = (const int*)  d_in[5];
    float* out = (float*)d_out;
    float* ws  = (float*)d_ws;

    const int n_ex = in_sizes[2];          // t has N_EX elements
    const int nW4  = in_sizes[1] / 4;      // W floats / 4
    const int nx4  = in_sizes[0] / 4;      // x floats / 4

    // 1) Warm L3 with a streaming pass over W and x (~237 MB @ ~6.3 TB/s).
    hsm_prefetch_kernel<<<4096, 256, 0, stream>>>(
        (const float4*)W, nW4, (const float4*)x, nx4, ws);

    // 2) Gather + dots: one wave per (example, step-pair).
    const int n_waves  = n_ex * HS_PAIRS;
    const int n_blocks = (n_waves + 3) / 4;   // 4 waves per 256-thr block
    hsm_pair_kernel<<<n_blocks, 256, 0, stream>>>(x, W, t, paths, codes, lens, ws);

    // 3) Reduce per-wave slots to the scalar loss.
    hsm_finish_kernel<<<1, 1024, 0, stream>>>(ws, n_waves, out);
}

// Round 6
// 335.436 us; speedup vs baseline: 1.1842x; 1.1842x over previous
//
#include <hip/hip_runtime.h>
#include <math.h>

// Problem constants (match reference.py)
#define HS_D      1024   // input_size
#define HS_MAXLEN 24     // max Huffman path depth
#define HS_QPW    6      // waves per example (each covers 4 path steps)

// One WAVE per (example, step-quad q): steps {2q, 2q+1, 2q+12, 2q+13}.
//  - x[n] fragment loaded ONCE per wave (4 float4), shared by 4 dots.
//  - up to 16 W-row float4 loads issued back-to-back (MLP) — only for VALID
//    steps (scalar branches; no wasted rows, the R1 mistake).
//  - __launch_bounds__(256,4): VGPR cap 128 so all ~20 loads stay in flight
//    (R1 showed the compiler rolls the window at the default 64-VGPR budget).
//  - readfirstlane forces scalar metadata loads + SCC branches.
//  - result -> private ws slot (no atomics, no zero-init dispatch).
__global__ __launch_bounds__(256, 4) void hsm_quad_kernel(
    const float* __restrict__ x,      // [N_EX, D]
    const float* __restrict__ W,      // [N_DEC, D]
    const int*   __restrict__ t,      // [N_EX]
    const int*   __restrict__ paths,  // [V, MAX_LEN]
    const float* __restrict__ codes,  // [V, MAX_LEN]
    const int*   __restrict__ lens,   // [V]
    float*       __restrict__ ws)     // [N_EX*HS_QPW] per-wave slots
{
    const int tid  = threadIdx.x;
    const int lane = tid & 63;
    const int wv   = __builtin_amdgcn_readfirstlane(tid >> 6);  // scalar wave id
    const int gw   = blockIdx.x * 4 + wv;
    const int n    = gw / HS_QPW;      // example
    const int q    = gw % HS_QPW;      // step-quad

    const int leaf = t[n];             // scalar load
    const int L    = lens[leaf];       // scalar load

    const int l0 = 2 * q;
    if (l0 >= L) {                     // scalar branch: wave fully invalid
        if (lane == 0) ws[gw] = 0.0f;  // slot must be written (ws poisoned)
        return;
    }
    const bool v1 = (l0 + 1)  < L;
    const bool v2 = (l0 + 12) < L;
    const bool v3 = (l0 + 13) < L;     // validity monotone: v1 >= v2 >= v3

    // Metadata: all 4 indices are in-bounds of the path row regardless of L
    // (row is fully populated), so load unconditionally -> scalar loads.
    const int base = leaf * HS_MAXLEN + l0;
    const int   nd0 = paths[base];      const float cd0 = codes[base];
    const int   nd1 = paths[base + 1];  const float cd1 = codes[base + 1];
    const int   nd2 = paths[base + 12]; const float cd2 = codes[base + 12];
    const int   nd3 = paths[base + 13]; const float cd3 = codes[base + 13];

    const float4* w0 = (const float4*)(W + (size_t)nd0 * HS_D);
    const float4* w1 = (const float4*)(W + (size_t)nd1 * HS_D);
    const float4* w2 = (const float4*)(W + (size_t)nd2 * HS_D);
    const float4* w3 = (const float4*)(W + (size_t)nd3 * HS_D);
    const float4* x4 = (const float4*)(x + (size_t)n   * HS_D);

    // Issue all loads before consuming any. W rows first (the misses);
    // x last (likely L1-shared with neighbor waves of the same example).
    float4 wf0[4], wf1[4], wf2[4], wf3[4], xf[4];
#pragma unroll
    for (int j = 0; j < 4; ++j) wf0[j] = w0[j * 64 + lane];
    if (v1) {
#pragma unroll
        for (int j = 0; j < 4; ++j) wf1[j] = w1[j * 64 + lane];
    } else {
#pragma unroll
        for (int j = 0; j < 4; ++j) wf1[j] = make_float4(0.f, 0.f, 0.f, 0.f);
    }
    if (v2) {
#pragma unroll
        for (int j = 0; j < 4; ++j) wf2[j] = w2[j * 64 + lane];
    } else {
#pragma unroll
        for (int j = 0; j < 4; ++j) wf2[j] = make_float4(0.f, 0.f, 0.f, 0.f);
    }
    if (v3) {
#pragma unroll
        for (int j = 0; j < 4; ++j) wf3[j] = w3[j * 64 + lane];
    } else {
#pragma unroll
        for (int j = 0; j < 4; ++j) wf3[j] = make_float4(0.f, 0.f, 0.f, 0.f);
    }
#pragma unroll
    for (int j = 0; j < 4; ++j) xf[j] = x4[j * 64 + lane];

    float d0 = 0.f, d1 = 0.f, d2 = 0.f, d3 = 0.f;
#pragma unroll
    for (int j = 0; j < 4; ++j) {
        d0 += xf[j].x * wf0[j].x + xf[j].y * wf0[j].y
            + xf[j].z * wf0[j].z + xf[j].w * wf0[j].w;
        d1 += xf[j].x * wf1[j].x + xf[j].y * wf1[j].y
            + xf[j].z * wf1[j].z + xf[j].w * wf1[j].w;
        d2 += xf[j].x * wf2[j].x + xf[j].y * wf2[j].y
            + xf[j].z * wf2[j].z + xf[j].w * wf2[j].w;
        d3 += xf[j].x * wf3[j].x + xf[j].y * wf3[j].y
            + xf[j].z * wf3[j].z + xf[j].w * wf3[j].w;
    }

    // Four interleaved 64-lane butterfly reductions.
#pragma unroll
    for (int off = 32; off > 0; off >>= 1) {
        d0 += __shfl_down(d0, off);
        d1 += __shfl_down(d1, off);
        d2 += __shfl_down(d2, off);
        d3 += __shfl_down(d3, off);
    }

    if (lane == 0) {
        const float z0 = -cd0 * d0;
        float v = fmaxf(z0, 0.f) + log1pf(expf(-fabsf(z0)));
        if (v1) {
            const float z1 = -cd1 * d1;
            v += fmaxf(z1, 0.f) + log1pf(expf(-fabsf(z1)));
        }
        if (v2) {
            const float z2 = -cd2 * d2;
            v += fmaxf(z2, 0.f) + log1pf(expf(-fabsf(z2)));
        }
        if (v3) {
            const float z3 = -cd3 * d3;
            v += fmaxf(z3, 0.f) + log1pf(expf(-fabsf(z3)));
        }
        ws[gw] = v;
    }
}

// Sum the per-wave slots -> scalar output. One 1024-thread block.
__global__ __launch_bounds__(1024) void hsm_finish_kernel(
    const float* __restrict__ ws, int n_slots, float* __restrict__ out)
{
    const int tid = threadIdx.x;
    float s = 0.0f;
    for (int i = tid; i < n_slots; i += 1024)
        s += ws[i];
#pragma unroll
    for (int off = 32; off > 0; off >>= 1)
        s += __shfl_down(s, off);
    __shared__ float sred[16];
    if ((tid & 63) == 0) sred[tid >> 6] = s;
    __syncthreads();
    if (tid == 0) {
        float tot = 0.0f;
#pragma unroll
        for (int w = 0; w < 16; ++w) tot += sred[w];
        out[0] = tot;
    }
}

extern "C" void kernel_launch(void* const* d_in, const int* in_sizes, int n_in,
                              void* d_out, int out_size, void* d_ws, size_t ws_size,
                              hipStream_t stream) {
    const float* x     = (const float*)d_in[0];
    const float* W     = (const float*)d_in[1];
    const int*   t     = (const int*)  d_in[2];
    const int*   paths = (const int*)  d_in[3];
    const float* codes = (const float*)d_in[4];
    const int*   lens  = (const int*)  d_in[5];
    float* out = (float*)d_out;
    float* ws  = (float*)d_ws;

    const int n_ex    = in_sizes[2];          // t has N_EX elements
    const int n_waves = n_ex * HS_QPW;        // 6 waves per example
    const int n_blocks = (n_waves + 3) / 4;   // 4 waves per 256-thr block

    hsm_quad_kernel<<<n_blocks, 256, 0, stream>>>(x, W, t, paths, codes, lens, ws);
    hsm_finish_kernel<<<1, 1024, 0, stream>>>(ws, n_waves, out);
}